// Round 1
// baseline (690.128 us; speedup 1.0000x reference)
//
#include <hip/hip_runtime.h>
#include <hip/hip_bf16.h>
#include <stdint.h>

#define LATF 256
#define NT 119
#define NNODES 100000
#define NEDGES 400000

typedef __attribute__((ext_vector_type(8))) short short8;
typedef __attribute__((ext_vector_type(4))) float f4;

__device__ __forceinline__ float bf2f(short u) {
  union { uint32_t i; float f; } v; v.i = ((uint32_t)(uint16_t)u) << 16; return v.f;
}
__device__ __forceinline__ short f2bf(float f) {
  union { float f; uint32_t i; } v; v.f = f;
  uint32_t r = (v.i + 0x7fffu + ((v.i >> 16) & 1u)) >> 16;
  return (short)(uint16_t)r;
}

// ---------------- prep: cast + build transposed weight layouts ----------------
__global__ __launch_bounds__(256) void prep_kernel(
    const float* __restrict__ lat, const float* __restrict__ pos,
    const float* __restrict__ nW1, const float* __restrict__ tW1, const float* __restrict__ dW1,
    const float* __restrict__ nW2, const float* __restrict__ tW2, const float* __restrict__ dW2,
    const float* __restrict__ nW3, const float* __restrict__ tW3, const float* __restrict__ dW3,
    short* __restrict__ latent_bf, short* __restrict__ pos_bf,
    short* __restrict__ Wtcat, short* __restrict__ Wt2cat,
    short* __restrict__ Wt3n, short* __restrict__ Wt3t, short* __restrict__ Wt3d)
{
  int i = blockIdx.x * 256 + threadIdx.x;
  if (i < 524288) { latent_bf[i] = f2bf(lat[i]); return; }
  i -= 524288;
  if (i < 800000) { pos_bf[i] = f2bf(pos[i]); return; }
  i -= 800000;
  if (i < 1280 * 288) {               // Wtcat[n][k], n-major, K padded 264->288
    int n = i / 288, k = i % 288;
    float v = 0.f;
    if (k < 264) {
      if (n < 256)       v = nW1[k * 256 + n];
      else if (n < 512)  v = tW1[k * 256 + (n - 256)];
      else if (n < 768)  v = tW1[(264 + k) * 256 + (n - 512)];
      else if (n < 1024) v = dW1[k * 256 + (n - 768)];
      else               v = dW1[(264 + k) * 256 + (n - 1024)];
    }
    Wtcat[n * 288 + k] = f2bf(v);
    return;
  }
  i -= 1280 * 288;
  if (i < 384 * 256) {                // Wt2cat[n][k]: rows 0-127 nW2, 128-255 tW2, 256-383 dW2
    int n = i / 256, k = i % 256;
    float v = (n < 128) ? nW2[k * 128 + n] : (n < 256) ? tW2[k * 128 + (n - 128)]
                                                       : dW2[k * 128 + (n - 256)];
    Wt2cat[n * 256 + k] = f2bf(v);
    return;
  }
  i -= 384 * 256;
  if (i < 128 * 128) {                // Wt3n[n][k], n padded 119->128
    int n = i / 128, k = i % 128;
    Wt3n[i] = (n < NT) ? f2bf(nW3[k * NT + n]) : (short)0;
    return;
  }
  i -= 128 * 128;
  if (i < 4 * 128) { int n = i / 128, k = i % 128; Wt3t[i] = f2bf(tW3[k * 4 + n]); return; }
  i -= 512;
  if (i < 3 * 128) { int n = i / 128, k = i % 128; Wt3d[i] = f2bf(dW3[k * 3 + n]); return; }
}

// ---------------- K1: nodeFeat x [nW1 | tW1_src | tW1_dst | dW1_src | dW1_dst] ----------------
// M=100000, K=288 (pad), N=1280. BM=64, BN=128, 4 waves (2x2), each wave 32x64.
__global__ __launch_bounds__(256) void k1_gemm(
    const short* __restrict__ latent_bf, const short* __restrict__ pos_bf,
    const int* __restrict__ batch, const short* __restrict__ Wtcat,
    const float* __restrict__ nb1, short* __restrict__ h1_node, short* __restrict__ Pall)
{
  __shared__ short As[64 * 40];   // 32 K-elems + pad 8 -> row stride 80B (2-way max)
  const int t = threadIdx.x;
  const int bm0 = blockIdx.x * 64;
  const int n0 = blockIdx.y * 128;
  const int wid = t >> 6, lane = t & 63;
  const int wm = wid >> 1, wn = wid & 1;
  const int lrow = lane & 15, kq = lane >> 4;

  const int sr = t >> 2, sq = t & 3;          // staging: 4 threads per row
  const int m_stage = bm0 + sr;
  const bool svalid = (m_stage < NNODES);
  const int g = svalid ? batch[m_stage] : 0;

  f4 acc[2][4];
  #pragma unroll
  for (int a = 0; a < 2; ++a)
    #pragma unroll
    for (int b = 0; b < 4; ++b) acc[a][b] = (f4){0.f, 0.f, 0.f, 0.f};

  for (int kc = 0; kc < 9; ++kc) {
    const int k0 = kc * 32;
    short8 av = {0, 0, 0, 0, 0, 0, 0, 0};
    if (svalid) {
      if (k0 < 256)      av = *(const short8*)(latent_bf + g * 256 + k0 + sq * 8);
      else if (sq == 0)  av = *(const short8*)(pos_bf + m_stage * 8);
    }
    *(short8*)(As + sr * 40 + sq * 8) = av;
    __syncthreads();

    short8 af[2];
    #pragma unroll
    for (int mf = 0; mf < 2; ++mf)
      af[mf] = *(const short8*)(As + (wm * 32 + mf * 16 + lrow) * 40 + kq * 8);
    #pragma unroll
    for (int nf = 0; nf < 4; ++nf) {
      const int ncol = n0 + wn * 64 + nf * 16 + lrow;
      short8 bfv = *(const short8*)(Wtcat + ncol * 288 + k0 + kq * 8);
      acc[0][nf] = __builtin_amdgcn_mfma_f32_16x16x32_bf16(af[0], bfv, acc[0][nf], 0, 0, 0);
      acc[1][nf] = __builtin_amdgcn_mfma_f32_16x16x32_bf16(af[1], bfv, acc[1][nf], 0, 0, 0);
    }
    __syncthreads();
  }

  #pragma unroll
  for (int mf = 0; mf < 2; ++mf)
    #pragma unroll
    for (int nf = 0; nf < 4; ++nf) {
      const int nglob = n0 + wn * 64 + nf * 16 + lrow;
      #pragma unroll
      for (int r = 0; r < 4; ++r) {
        const int m = bm0 + wm * 32 + mf * 16 + kq * 4 + r;
        if (m < NNODES) {
          float v = acc[mf][nf][r];
          if (nglob < 256) {
            float h = v + nb1[nglob];
            h1_node[m * 256 + nglob] = f2bf(h > 0.f ? h : 0.f);
          } else {
            Pall[m * 1024 + (nglob - 256)] = f2bf(v);
          }
        }
      }
    }
}

// ---------------- K2: node tail 256 -> 128(relu) -> 119 ----------------
__global__ __launch_bounds__(256) void k2_node_tail(
    const short* __restrict__ h1_node, const short* __restrict__ Wt2cat,
    const short* __restrict__ Wt3n, const float* __restrict__ nb2,
    const float* __restrict__ nb3, float* __restrict__ out_node)
{
  __shared__ short h2s[64 * 136];
  const int t = threadIdx.x;
  const int bm0 = blockIdx.x * 64;
  const int wid = t >> 6, lane = t & 63;
  const int wm = wid >> 1, wn = wid & 1;
  const int lrow = lane & 15, kq = lane >> 4;

  f4 acc[2][4];
  #pragma unroll
  for (int a = 0; a < 2; ++a)
    #pragma unroll
    for (int b = 0; b < 4; ++b) acc[a][b] = (f4){0.f, 0.f, 0.f, 0.f};

  #pragma unroll
  for (int kc = 0; kc < 8; ++kc) {
    short8 af[2];
    #pragma unroll
    for (int mf = 0; mf < 2; ++mf) {
      const int m = bm0 + wm * 32 + mf * 16 + lrow;
      if (m < NNODES) af[mf] = *(const short8*)(h1_node + m * 256 + kc * 32 + kq * 8);
      else            af[mf] = (short8){0, 0, 0, 0, 0, 0, 0, 0};
    }
    #pragma unroll
    for (int nf = 0; nf < 4; ++nf) {
      const int ncol = wn * 64 + nf * 16 + lrow;
      short8 bfv = *(const short8*)(Wt2cat + ncol * 256 + kc * 32 + kq * 8);
      acc[0][nf] = __builtin_amdgcn_mfma_f32_16x16x32_bf16(af[0], bfv, acc[0][nf], 0, 0, 0);
      acc[1][nf] = __builtin_amdgcn_mfma_f32_16x16x32_bf16(af[1], bfv, acc[1][nf], 0, 0, 0);
    }
  }
  #pragma unroll
  for (int mf = 0; mf < 2; ++mf)
    #pragma unroll
    for (int nf = 0; nf < 4; ++nf) {
      const int n = wn * 64 + nf * 16 + lrow;
      #pragma unroll
      for (int r = 0; r < 4; ++r) {
        const int ml = wm * 32 + mf * 16 + kq * 4 + r;
        float h = acc[mf][nf][r] + nb2[n];
        h2s[ml * 136 + n] = f2bf(h > 0.f ? h : 0.f);
      }
    }
  __syncthreads();

  f4 acc2[2][4];
  #pragma unroll
  for (int a = 0; a < 2; ++a)
    #pragma unroll
    for (int b = 0; b < 4; ++b) acc2[a][b] = (f4){0.f, 0.f, 0.f, 0.f};

  #pragma unroll
  for (int kc = 0; kc < 4; ++kc) {
    short8 af[2];
    #pragma unroll
    for (int mf = 0; mf < 2; ++mf)
      af[mf] = *(const short8*)(h2s + (wm * 32 + mf * 16 + lrow) * 136 + kc * 32 + kq * 8);
    #pragma unroll
    for (int nf = 0; nf < 4; ++nf) {
      const int ncol = wn * 64 + nf * 16 + lrow;
      short8 bfv = *(const short8*)(Wt3n + ncol * 128 + kc * 32 + kq * 8);
      acc2[0][nf] = __builtin_amdgcn_mfma_f32_16x16x32_bf16(af[0], bfv, acc2[0][nf], 0, 0, 0);
      acc2[1][nf] = __builtin_amdgcn_mfma_f32_16x16x32_bf16(af[1], bfv, acc2[1][nf], 0, 0, 0);
    }
  }
  #pragma unroll
  for (int mf = 0; mf < 2; ++mf)
    #pragma unroll
    for (int nf = 0; nf < 4; ++nf) {
      const int n = wn * 64 + nf * 16 + lrow;
      #pragma unroll
      for (int r = 0; r < 4; ++r) {
        const int m = bm0 + wm * 32 + mf * 16 + kq * 4 + r;
        if (m < NNODES && n < NT) out_node[m * NT + n] = acc2[mf][nf][r] + nb3[n];
      }
    }
}

// ---------------- K3: edge tail (type + dir phases) ----------------
__global__ __launch_bounds__(256) void k3_edge(
    const short* __restrict__ Pall, const int* __restrict__ eidx,
    const short* __restrict__ Wt2cat, const short* __restrict__ Wt3t, const short* __restrict__ Wt3d,
    const float* __restrict__ tb1, const float* __restrict__ tb2, const float* __restrict__ tb3,
    const float* __restrict__ db1, const float* __restrict__ db2, const float* __restrict__ db3,
    float* __restrict__ out_t, float* __restrict__ out_d)
{
  __shared__ short h1s[64 * 264];   // row stride 528B -> 2-way max
  __shared__ short h2s[64 * 136];
  __shared__ float b1s[256];
  __shared__ int ss[64], dd[64];

  const int t = threadIdx.x;
  const int e0 = blockIdx.x * 64;
  if (t < 64) {
    const int e = e0 + t;
    ss[t] = (e < NEDGES) ? eidx[e] : 0;
    dd[t] = (e < NEDGES) ? eidx[NEDGES + e] : 0;
  }
  const int wid = t >> 6, lane = t & 63;
  const int wm = wid >> 1, wn = wid & 1;
  const int lrow = lane & 15, kq = lane >> 4;
  const int gr = t >> 2, gq = t & 3;

  for (int ph = 0; ph < 2; ++ph) {
    const float* b1 = ph ? db1 : tb1;
    const float* b2 = ph ? db2 : tb2;
    const float* b3 = ph ? db3 : tb3;
    const short* W3 = ph ? Wt3d : Wt3t;
    const int poff1 = ph ? 512 : 0;
    const int poff2 = ph ? 768 : 256;
    const int w2row0 = 128 + ph * 128;

    b1s[t] = b1[t];
    __syncthreads();    // b1s ready; prior phase done with h1s/h2s

    { // gather + bias + relu -> h1s
      const long sbase = (long)ss[gr] * 1024 + poff1;
      const long dbase = (long)dd[gr] * 1024 + poff2;
      #pragma unroll
      for (int c = 0; c < 8; ++c) {
        const int j0 = (gq + c * 4) * 8;
        short8 v1 = *(const short8*)(Pall + sbase + j0);
        short8 v2 = *(const short8*)(Pall + dbase + j0);
        short8 o;
        #pragma unroll
        for (int x = 0; x < 8; ++x) {
          float f = bf2f(v1[x]) + bf2f(v2[x]) + b1s[j0 + x];
          o[x] = f2bf(f > 0.f ? f : 0.f);
        }
        *(short8*)(h1s + gr * 264 + j0) = o;
      }
    }
    __syncthreads();

    f4 acc[2][4];
    #pragma unroll
    for (int a = 0; a < 2; ++a)
      #pragma unroll
      for (int b = 0; b < 4; ++b) acc[a][b] = (f4){0.f, 0.f, 0.f, 0.f};

    #pragma unroll
    for (int kc = 0; kc < 8; ++kc) {
      short8 af[2];
      #pragma unroll
      for (int mf = 0; mf < 2; ++mf)
        af[mf] = *(const short8*)(h1s + (wm * 32 + mf * 16 + lrow) * 264 + kc * 32 + kq * 8);
      #pragma unroll
      for (int nf = 0; nf < 4; ++nf) {
        const int ncol = w2row0 + wn * 64 + nf * 16 + lrow;
        short8 bfv = *(const short8*)(Wt2cat + ncol * 256 + kc * 32 + kq * 8);
        acc[0][nf] = __builtin_amdgcn_mfma_f32_16x16x32_bf16(af[0], bfv, acc[0][nf], 0, 0, 0);
        acc[1][nf] = __builtin_amdgcn_mfma_f32_16x16x32_bf16(af[1], bfv, acc[1][nf], 0, 0, 0);
      }
    }
    #pragma unroll
    for (int mf = 0; mf < 2; ++mf)
      #pragma unroll
      for (int nf = 0; nf < 4; ++nf) {
        const int n = wn * 64 + nf * 16 + lrow;
        #pragma unroll
        for (int r = 0; r < 4; ++r) {
          const int ml = wm * 32 + mf * 16 + kq * 4 + r;
          float h = acc[mf][nf][r] + b2[n];
          h2s[ml * 136 + n] = f2bf(h > 0.f ? h : 0.f);
        }
      }
    __syncthreads();

    { // layer 3: tiny N, plain dot products (one thread per edge x col)
      const int e = t >> 2, n = t & 3;
      const int ncols = ph ? 3 : 4;
      const int eg = e0 + e;
      if (n < ncols && eg < NEDGES) {
        float s = 0.f;
        #pragma unroll
        for (int kk = 0; kk < 16; ++kk) {
          short8 hv = *(const short8*)(h2s + e * 136 + kk * 8);
          short8 wv = *(const short8*)(W3 + n * 128 + kk * 8);
          #pragma unroll
          for (int x = 0; x < 8; ++x) s += bf2f(hv[x]) * bf2f(wv[x]);
        }
        if (ph == 0) out_t[eg * 4 + n] = s + b3[n];
        else         out_d[eg * 3 + n] = s + b3[n];
      }
    }
    // next phase's first barrier orders h1s/h2s reuse
  }
}

extern "C" void kernel_launch(void* const* d_in, const int* in_sizes, int n_in,
                              void* d_out, int out_size, void* d_ws, size_t ws_size,
                              hipStream_t stream)
{
  const float* lat = (const float*)d_in[0];
  const float* pos = (const float*)d_in[1];
  const int* batch = (const int*)d_in[2];
  const int* eidx  = (const int*)d_in[3];
  const float* nW1 = (const float*)d_in[4];  const float* nb1 = (const float*)d_in[5];
  const float* nW2 = (const float*)d_in[6];  const float* nb2 = (const float*)d_in[7];
  const float* nW3 = (const float*)d_in[8];  const float* nb3 = (const float*)d_in[9];
  const float* tW1 = (const float*)d_in[10]; const float* tb1 = (const float*)d_in[11];
  const float* tW2 = (const float*)d_in[12]; const float* tb2 = (const float*)d_in[13];
  const float* tW3 = (const float*)d_in[14]; const float* tb3 = (const float*)d_in[15];
  const float* dW1 = (const float*)d_in[16]; const float* db1 = (const float*)d_in[17];
  const float* dW2 = (const float*)d_in[18]; const float* db2 = (const float*)d_in[19];
  const float* dW3 = (const float*)d_in[20]; const float* db3 = (const float*)d_in[21];

  char* ws = (char*)d_ws;
  short* latent_bf = (short*)(ws + 0);          //   1,048,576 B
  short* pos_bf    = (short*)(ws + 1048576);    //   1,600,000 B
  short* Wtcat     = (short*)(ws + 2648576);    //     737,280 B
  short* Wt2cat    = (short*)(ws + 3385856);    //     196,608 B
  short* Wt3n      = (short*)(ws + 3582464);    //      32,768 B
  short* Wt3t      = (short*)(ws + 3615232);    //       1,024 B
  short* Wt3d      = (short*)(ws + 3616256);    //       1,024 B (768 used)
  short* h1_node   = (short*)(ws + 3617280);    //  51,200,000 B
  short* Pall      = (short*)(ws + 54817280);   // 204,800,000 B  -> total ~259.6 MB

  float* out_node = (float*)d_out;
  float* out_t = out_node + (size_t)NNODES * NT;
  float* out_d = out_t + (size_t)NEDGES * 4;

  prep_kernel<<<7065, 256, 0, stream>>>(lat, pos, nW1, tW1, dW1, nW2, tW2, dW2,
                                        nW3, tW3, dW3, latent_bf, pos_bf, Wtcat,
                                        Wt2cat, Wt3n, Wt3t, Wt3d);
  k1_gemm<<<dim3(1563, 10), 256, 0, stream>>>(latent_bf, pos_bf, batch, Wtcat,
                                              nb1, h1_node, Pall);
  k2_node_tail<<<1563, 256, 0, stream>>>(h1_node, Wt2cat, Wt3n, nb2, nb3, out_node);
  k3_edge<<<6250, 256, 0, stream>>>(Pall, eidx, Wt2cat, Wt3t, Wt3d,
                                    tb1, tb2, tb3, db1, db2, db3, out_t, out_d);
}